// Round 5
// baseline (3089.513 us; speedup 1.0000x reference)
//
#include <hip/hip_runtime.h>
#include <hip/hip_bf16.h>

// combined bucket space: um buckets [0,625) width 32; mu buckets [625,1407) width 128
#define NB_UM 625
#define NB_MU 782
#define NBALL 1407
#define NBLK 256

// ---------------- pass 1: per-(bucket,block) histogram ----------------

__global__ __launch_bounds__(1024) void hist_part(const int* __restrict__ dst_um,
                                                  const int* __restrict__ dst_mu,
                                                  int* __restrict__ histM, int E) {
    __shared__ int h[NBALL];
    for (int i = threadIdx.x; i < NBALL; i += 1024) h[i] = 0;
    __syncthreads();
    int blk = blockIdx.x;
    int chunk = (E + NBLK - 1) / NBLK;
    int s = blk * chunk, e = min(E, s + chunk);
    for (int i = s + threadIdx.x; i < e; i += 1024) {
        atomicAdd(&h[dst_um[i] >> 5], 1);
        atomicAdd(&h[NB_UM + (dst_mu[i] >> 7)], 1);
    }
    __syncthreads();
    for (int i = threadIdx.x; i < NBALL; i += 1024) histM[i * NBLK + blk] = h[i];
}

// ---------------- pass 2: per-bucket wave scan over blocks ----------------

__global__ __launch_bounds__(256) void bucket_totals(int* __restrict__ histM,
                                                     int* __restrict__ btot, int nball) {
    int w = (blockIdx.x * blockDim.x + threadIdx.x) >> 6;
    int lane = threadIdx.x & 63;
    if (w >= nball) return;
    int* row = histM + w * NBLK;
    int v[4];
    int s = 0;
#pragma unroll
    for (int i = 0; i < 4; i++) {
        int c = row[lane * 4 + i];
        v[i] = s;
        s += c;
    }
    int incl = s;
    for (int d = 1; d < 64; d <<= 1) {
        int y = __shfl_up(incl, d, 64);
        if (lane >= d) incl += y;
    }
    int excl = incl - s;
#pragma unroll
    for (int i = 0; i < 4; i++) row[lane * 4 + i] = excl + v[i];
    if (lane == 63) btot[w] = incl;
}

// ---------------- pass 3: scan bucket totals ----------------

__global__ __launch_bounds__(256) void boff_scan(const int* __restrict__ btot,
                                                 int* __restrict__ boff, int nball, int E) {
    __shared__ int sdata[256];
    int t = threadIdx.x;
    int v[8];
    int sum = 0;
#pragma unroll
    for (int i = 0; i < 8; i++) {
        int idx = t * 8 + i;
        int c = (idx < nball) ? btot[idx] : 0;
        v[i] = sum;
        sum += c;
    }
    sdata[t] = sum;
    __syncthreads();
    for (int s = 1; s < 256; s <<= 1) {
        int y = (t >= s) ? sdata[t - s] : 0;
        __syncthreads();
        sdata[t] += y;
        __syncthreads();
    }
    int base = (t == 0) ? 0 : sdata[t - 1];
#pragma unroll
    for (int i = 0; i < 8; i++) {
        int idx = t * 8 + i;
        if (idx < nball) boff[idx] = base + v[i];
    }
    if (t == 0) boff[nball] = 2 * E;
}

// ---------------- pass 4: finalize off_mat ----------------

__global__ __launch_bounds__(256) void add_boff(int* __restrict__ histM,
                                                const int* __restrict__ boff, int n) {
    int st = gridDim.x * blockDim.x;
    for (int i = blockIdx.x * blockDim.x + threadIdx.x; i < n; i += st)
        histM[i] += boff[i >> 8];  // NBLK==256
}

// ---------------- pass 5: partition (block-private cursors in LDS) ----------------

__global__ __launch_bounds__(1024) void partition2(const int* __restrict__ src_um,
                                                   const int* __restrict__ dst_um,
                                                   const int* __restrict__ src_mu,
                                                   const int* __restrict__ dst_mu,
                                                   const int* __restrict__ histM,
                                                   int* __restrict__ tmp, int E) {
    __shared__ int cur[NBALL];
    int blk = blockIdx.x;
    for (int i = threadIdx.x; i < NBALL; i += 1024) cur[i] = histM[i * NBLK + blk];
    __syncthreads();
    int chunk = (E + NBLK - 1) / NBLK;
    int s = blk * chunk, e = min(E, s + chunk);
    for (int i = s + threadIdx.x; i < e; i += 1024) {
        int d = dst_um[i];
        int p = atomicAdd(&cur[d >> 5], 1);
        tmp[p] = src_um[i] | ((d & 31) << 20);
        int d2 = dst_mu[i];
        int q = atomicAdd(&cur[NB_UM + (d2 >> 7)], 1);
        tmp[q] = src_mu[i] | ((d2 & 127) << 20);
    }
}

// ---------------- bucket-direct segment mean (LDS accumulators) ----------------
// One block per bucket of W dsts. acc stride D+1 breaks stride-64 bank pattern.

template <int D, int W, int NT>
__global__ __launch_bounds__(NT) void agg_bucket(const int* __restrict__ tmp,
                                                 const int* __restrict__ boff, int bbase,
                                                 const float* __restrict__ x,
                                                 float* __restrict__ out, int nrows) {
    constexpr int SD = D + 1;
    constexpr int LPE = D / 4;      // lanes per edge
    constexpr int EPI = NT / LPE;   // edges per iteration
    constexpr int U = 4;            // unroll (independent gathers in flight)
    __shared__ float acc[W * SD];
    __shared__ int cnt[W];
    int t = threadIdx.x;
    for (int i = t; i < W * SD; i += NT) acc[i] = 0.f;
    for (int i = t; i < W; i += NT) cnt[i] = 0;
    __syncthreads();
    int b = blockIdx.x;
    int s = boff[bbase + b], e = boff[bbase + b + 1];
    int g = t / LPE;
    int cl = (t % LPE) * 4;
    for (int base = s + g; base < e; base += EPI * U) {
        float4 vals[U];
        int locs[U];
#pragma unroll
        for (int u = 0; u < U; u++) {
            int i = base + u * EPI;
            locs[u] = -1;
            if (i < e) {
                int v = tmp[i];
                locs[u] = v >> 20;
                vals[u] = *(const float4*)&x[(long)(v & 0xFFFFF) * D + cl];
            }
        }
#pragma unroll
        for (int u = 0; u < U; u++) {
            if (locs[u] >= 0) {
                float* a = &acc[locs[u] * SD + cl];
                atomicAdd(a + 0, vals[u].x);
                atomicAdd(a + 1, vals[u].y);
                atomicAdd(a + 2, vals[u].z);
                atomicAdd(a + 3, vals[u].w);
                if (cl == 0) atomicAdd(&cnt[locs[u]], 1);
            }
        }
    }
    __syncthreads();
    for (int i = t; i < W * LPE; i += NT) {
        int loc = i / LPE, c = (i % LPE) * 4;
        int gr = b * W + loc;
        if (gr < nrows) {
            float inv = 1.0f / fmaxf((float)cnt[loc], 1.0f);
            const float* a = &acc[loc * SD + c];
            float4 r = make_float4(a[0] * inv, a[1] * inv, a[2] * inv, a[3] * inv);
            *(float4*)&out[(long)gr * D + c] = r;
        }
    }
}

// ---------------- dense: out = act([mean|xd] @ [Wl;Wr] + b) ----------------

template <int Dm, int Dd, bool RELU>
__global__ __launch_bounds__(256) void dense_gemm(const float* __restrict__ mean,
                                                  const float* __restrict__ xd,
                                                  const float* __restrict__ Wl,
                                                  const float* __restrict__ Wr,
                                                  const float* __restrict__ bias,
                                                  float* __restrict__ out, int n) {
    constexpr int K = Dm + Dd;
    __shared__ float sA[64][K + 4];
    __shared__ float sW[K][68];
    __shared__ float sb[64];
    int t = threadIdx.x;
    int R0 = blockIdx.x * 64;

    for (int i = t; i < K * 16; i += 256) {
        int r = i >> 4, c = (i & 15) * 4;
        float4 v = (r < Dm) ? *(const float4*)&Wl[r * 64 + c]
                            : *(const float4*)&Wr[(r - Dm) * 64 + c];
        sW[r][c + 0] = v.x; sW[r][c + 1] = v.y; sW[r][c + 2] = v.z; sW[r][c + 3] = v.w;
    }
    if (t < 64) sb[t] = bias[t];
    constexpr int QR = K / 4;
    for (int i = t; i < 64 * QR; i += 256) {
        int r = i / QR, c = (i % QR) * 4;
        int gr = R0 + r;
        float4 v = make_float4(0.f, 0.f, 0.f, 0.f);
        if (gr < n)
            v = (c < Dm) ? *(const float4*)&mean[(long)gr * Dm + c]
                         : *(const float4*)&xd[(long)gr * Dd + (c - Dm)];
        sA[r][c + 0] = v.x; sA[r][c + 1] = v.y; sA[r][c + 2] = v.z; sA[r][c + 3] = v.w;
    }
    __syncthreads();

    int tx = t & 15, ty = t >> 4;
    int c0 = tx * 4, r0 = ty * 4;
    float acc[4][4];
    float4 bb = *(float4*)&sb[c0];
#pragma unroll
    for (int i = 0; i < 4; i++) {
        acc[i][0] = bb.x; acc[i][1] = bb.y; acc[i][2] = bb.z; acc[i][3] = bb.w;
    }
#pragma unroll 4
    for (int k = 0; k < K; k += 4) {
        float4 a[4], b[4];
#pragma unroll
        for (int i = 0; i < 4; i++) a[i] = *(float4*)&sA[r0 + i][k];
#pragma unroll
        for (int kk = 0; kk < 4; kk++) b[kk] = *(float4*)&sW[k + kk][c0];
#pragma unroll
        for (int i = 0; i < 4; i++) {
            acc[i][0] += a[i].x * b[0].x + a[i].y * b[1].x + a[i].z * b[2].x + a[i].w * b[3].x;
            acc[i][1] += a[i].x * b[0].y + a[i].y * b[1].y + a[i].z * b[2].y + a[i].w * b[3].y;
            acc[i][2] += a[i].x * b[0].z + a[i].y * b[1].z + a[i].z * b[2].z + a[i].w * b[3].z;
            acc[i][3] += a[i].x * b[0].w + a[i].y * b[1].w + a[i].z * b[2].w + a[i].w * b[3].w;
        }
    }
#pragma unroll
    for (int i = 0; i < 4; i++) {
        int gr = R0 + r0 + i;
        if (gr >= n) continue;
        float4 r;
        if (RELU) {
            r = make_float4(fmaxf(acc[i][0], 0.f), fmaxf(acc[i][1], 0.f),
                            fmaxf(acc[i][2], 0.f), fmaxf(acc[i][3], 0.f));
        } else {
            r = make_float4(acc[i][0], acc[i][1], acc[i][2], acc[i][3]);
        }
        *(float4*)&out[(long)gr * 64 + c0] = r;
    }
}

// ---------------- head ----------------

__global__ __launch_bounds__(256) void head_kernel(const float* __restrict__ z_user,
                                                   const float* __restrict__ z_movie,
                                                   const int* __restrict__ lrow,
                                                   const int* __restrict__ lcol,
                                                   const float* __restrict__ Wlin,
                                                   const float* __restrict__ blin,
                                                   float* __restrict__ out, int B) {
    int wave = (blockIdx.x * blockDim.x + threadIdx.x) >> 6;
    int lane = threadIdx.x & 63;
    int nw = (gridDim.x * blockDim.x) >> 6;
    for (int b = wave; b < B; b += nw) {
        int r = lrow[b], c = lcol[b];
        float zu = z_user[(long)r * 64 + lane];
        float zm = z_movie[(long)c * 64 + lane];
        float p0 = zu * Wlin[lane * 2 + 0] + zm * Wlin[(64 + lane) * 2 + 0];
        float p1 = zu * Wlin[lane * 2 + 1] + zm * Wlin[(64 + lane) * 2 + 1];
        for (int s = 32; s; s >>= 1) {
            p0 += __shfl_xor(p0, s, 64);
            p1 += __shfl_xor(p1, s, 64);
        }
        if (lane == 0) {
            float m = p0 + blin[0];
            float x = p1 + blin[1];
            float sp = fmaxf(x, 0.f) + log1pf(expf(-fabsf(x)));
            out[b] = m;
            out[B + b] = sp + 1e-6f;
        }
    }
}

// ---------------- launch ----------------

extern "C" void kernel_launch(void* const* d_in, const int* in_sizes, int n_in,
                              void* d_out, int out_size, void* d_ws, size_t ws_size,
                              hipStream_t stream) {
    const float* x_user  = (const float*)d_in[0];
    const float* x_movie = (const float*)d_in[1];
    const int* src_um = (const int*)d_in[2];
    const int* dst_um = (const int*)d_in[3];
    const int* src_mu = (const int*)d_in[4];
    const int* dst_mu = (const int*)d_in[5];
    const int* lrow = (const int*)d_in[6];
    const int* lcol = (const int*)d_in[7];
    const float* W1_um_l = (const float*)d_in[8];
    const float* b1_um   = (const float*)d_in[9];
    const float* W1_um_r = (const float*)d_in[10];
    const float* W1_mu_l = (const float*)d_in[11];
    const float* b1_mu   = (const float*)d_in[12];
    const float* W1_mu_r = (const float*)d_in[13];
    const float* W2_um_l = (const float*)d_in[14];
    const float* b2_um   = (const float*)d_in[15];
    const float* W2_um_r = (const float*)d_in[16];
    const float* W2_mu_l = (const float*)d_in[17];
    const float* b2_mu   = (const float*)d_in[18];
    const float* W2_mu_r = (const float*)d_in[19];
    const float* W_lin   = (const float*)d_in[20];
    const float* b_lin   = (const float*)d_in[21];
    float* out = (float*)d_out;

    const int E  = in_sizes[2];
    const int B  = in_sizes[6];
    const int NU = in_sizes[0] / 32;   // 100000
    const int NM = in_sizes[1] / 64;   // 20000

    char* wsp = (char*)d_ws;
    size_t o = 0;
    auto alloc = [&](size_t bytes) {
        size_t p = o;
        o += (bytes + 255) & ~(size_t)255;
        return (void*)(wsp + p);
    };
    int* btot = (int*)alloc((NBALL) * 4);
    int* boff = (int*)alloc((NBALL + 1) * 4);
    int* tmp  = (int*)alloc((size_t)2 * E * 4);        // bucketed edges, lives through layer 2
    float* A_m = (float*)alloc((size_t)NM * 64 * 4);   // movie mean / z_movie
    float* A_u = (float*)alloc((size_t)NU * 64 * 4);   // user mean / z_user
    float* H_m = (float*)alloc((size_t)NM * 64 * 4);   // h_movie
    float* H_u = (float*)alloc((size_t)NU * 64 * 4);   // h_user
    (void)ws_size;

    // histM aliases H_m: dead after partition2, H_m first written by layer-1 dense
    int* histM = (int*)H_m;  // [NBALL*NBLK] = 1.44 MB

    // 1) CSR-by-bucket build (block-private radix partition)
    hist_part<<<NBLK, 1024, 0, stream>>>(dst_um, dst_mu, histM, E);
    bucket_totals<<<(NBALL + 3) / 4, 256, 0, stream>>>(histM, btot, NBALL);
    boff_scan<<<1, 256, 0, stream>>>(btot, boff, NBALL, E);
    add_boff<<<352, 256, 0, stream>>>(histM, boff, NBALL * NBLK);
    partition2<<<NBLK, 1024, 0, stream>>>(src_um, dst_um, src_mu, dst_mu, histM, tmp, E);

    // 2) layer 1
    agg_bucket<32, 32, 512><<<NB_UM, 512, 0, stream>>>(tmp, boff, 0, x_user, A_m, NM);
    dense_gemm<32, 64, true><<<(NM + 63) / 64, 256, 0, stream>>>(A_m, x_movie, W1_um_l, W1_um_r,
                                                                 b1_um, H_m, NM);
    agg_bucket<64, 128, 512><<<NB_MU, 512, 0, stream>>>(tmp, boff, NB_UM, x_movie, A_u, NU);
    dense_gemm<64, 32, true><<<(NU + 63) / 64, 256, 0, stream>>>(A_u, x_user, W1_mu_l, W1_mu_r,
                                                                 b1_mu, H_u, NU);

    // 3) layer 2 (dense in-place over the mean buffers; block stages rows before writing)
    agg_bucket<64, 32, 512><<<NB_UM, 512, 0, stream>>>(tmp, boff, 0, H_u, A_m, NM);
    dense_gemm<64, 64, false><<<(NM + 63) / 64, 256, 0, stream>>>(A_m, H_m, W2_um_l, W2_um_r,
                                                                  b2_um, A_m, NM);
    agg_bucket<64, 128, 512><<<NB_MU, 512, 0, stream>>>(tmp, boff, NB_UM, H_m, A_u, NU);
    dense_gemm<64, 64, false><<<(NU + 63) / 64, 256, 0, stream>>>(A_u, H_u, W2_mu_l, W2_mu_r,
                                                                  b2_mu, A_u, NU);

    // 4) head
    head_kernel<<<4096, 256, 0, stream>>>(A_u, A_m, lrow, lcol, W_lin, b_lin, out, B);
}

// Round 6
// 379.161 us; speedup vs baseline: 8.1483x; 8.1483x over previous
//
#include <hip/hip_runtime.h>
#include <hip/hip_bf16.h>
#include <hip/hip_fp16.h>
#include <type_traits>

// combined bucket space: um buckets [0,625) width 32; mu buckets [625,1407) width 128
#define NB_UM 625
#define NB_MU 782
#define NBALL 1407
#define NBLK 256

// ---------------- cast fp32 -> fp16 tables ----------------

__global__ __launch_bounds__(256) void cast_half2(const float* __restrict__ a,
                                                  __half* __restrict__ ah, int na,
                                                  const float* __restrict__ b,
                                                  __half* __restrict__ bh, int nb) {
    int i = blockIdx.x * blockDim.x + threadIdx.x;
    int st = gridDim.x * blockDim.x;
    for (int k = i; k < na / 2; k += st) {
        float2 v = ((const float2*)a)[k];
        ((__half2*)ah)[k] = __floats2half2_rn(v.x, v.y);
    }
    for (int k = i; k < nb / 2; k += st) {
        float2 v = ((const float2*)b)[k];
        ((__half2*)bh)[k] = __floats2half2_rn(v.x, v.y);
    }
}

// ---------------- pass 1: per-(bucket,block) histogram ----------------

__global__ __launch_bounds__(1024) void hist_part(const int* __restrict__ dst_um,
                                                  const int* __restrict__ dst_mu,
                                                  int* __restrict__ histM, int E) {
    __shared__ int h[NBALL];
    for (int i = threadIdx.x; i < NBALL; i += 1024) h[i] = 0;
    __syncthreads();
    int blk = blockIdx.x;
    int chunk = (E + NBLK - 1) / NBLK;
    int s = blk * chunk, e = min(E, s + chunk);
    for (int i = s + threadIdx.x; i < e; i += 1024) {
        atomicAdd(&h[dst_um[i] >> 5], 1);
        atomicAdd(&h[NB_UM + (dst_mu[i] >> 7)], 1);
    }
    __syncthreads();
    for (int i = threadIdx.x; i < NBALL; i += 1024) histM[i * NBLK + blk] = h[i];
}

// ---------------- pass 2: per-bucket wave scan over blocks ----------------

__global__ __launch_bounds__(256) void bucket_totals(int* __restrict__ histM,
                                                     int* __restrict__ btot, int nball) {
    int w = (blockIdx.x * blockDim.x + threadIdx.x) >> 6;
    int lane = threadIdx.x & 63;
    if (w >= nball) return;
    int* row = histM + w * NBLK;
    int v[4];
    int s = 0;
#pragma unroll
    for (int i = 0; i < 4; i++) {
        int c = row[lane * 4 + i];
        v[i] = s;
        s += c;
    }
    int incl = s;
    for (int d = 1; d < 64; d <<= 1) {
        int y = __shfl_up(incl, d, 64);
        if (lane >= d) incl += y;
    }
    int excl = incl - s;
#pragma unroll
    for (int i = 0; i < 4; i++) row[lane * 4 + i] = excl + v[i];
    if (lane == 63) btot[w] = incl;
}

// ---------------- pass 3: scan bucket totals ----------------

__global__ __launch_bounds__(256) void boff_scan(const int* __restrict__ btot,
                                                 int* __restrict__ boff, int nball,
                                                 int* __restrict__ off_um, int NM,
                                                 int* __restrict__ off_mu, int NU, int E) {
    __shared__ int sdata[256];
    int t = threadIdx.x;
    int v[8];
    int sum = 0;
#pragma unroll
    for (int i = 0; i < 8; i++) {
        int idx = t * 8 + i;
        int c = (idx < nball) ? btot[idx] : 0;
        v[i] = sum;
        sum += c;
    }
    sdata[t] = sum;
    __syncthreads();
    for (int s = 1; s < 256; s <<= 1) {
        int y = (t >= s) ? sdata[t - s] : 0;
        __syncthreads();
        sdata[t] += y;
        __syncthreads();
    }
    int base = (t == 0) ? 0 : sdata[t - 1];
#pragma unroll
    for (int i = 0; i < 8; i++) {
        int idx = t * 8 + i;
        if (idx < nball) boff[idx] = base + v[i];
    }
    if (t == 0) {
        boff[nball] = 2 * E;
        off_um[NM] = E;
        off_mu[NU] = E;
    }
}

// ---------------- pass 4: finalize off_mat ----------------

__global__ __launch_bounds__(256) void add_boff(int* __restrict__ histM,
                                                const int* __restrict__ boff, int n) {
    int st = gridDim.x * blockDim.x;
    for (int i = blockIdx.x * blockDim.x + threadIdx.x; i < n; i += st)
        histM[i] += boff[i >> 8];  // NBLK==256
}

// ---------------- pass 5: partition (block-private cursors in LDS) ----------------

__global__ __launch_bounds__(1024) void partition2(const int* __restrict__ src_um,
                                                   const int* __restrict__ dst_um,
                                                   const int* __restrict__ src_mu,
                                                   const int* __restrict__ dst_mu,
                                                   const int* __restrict__ histM,
                                                   int* __restrict__ tmp, int E) {
    __shared__ int cur[NBALL];
    int blk = blockIdx.x;
    for (int i = threadIdx.x; i < NBALL; i += 1024) cur[i] = histM[i * NBLK + blk];
    __syncthreads();
    int chunk = (E + NBLK - 1) / NBLK;
    int s = blk * chunk, e = min(E, s + chunk);
    for (int i = s + threadIdx.x; i < e; i += 1024) {
        int d = dst_um[i];
        int p = atomicAdd(&cur[d >> 5], 1);
        tmp[p] = src_um[i] | ((d & 31) << 20);
        int d2 = dst_mu[i];
        int q = atomicAdd(&cur[NB_UM + (d2 >> 7)], 1);
        tmp[q] = src_mu[i] | ((d2 & 127) << 20);
    }
}

// ---------------- pass 6: per-bucket CSR scatter ----------------

template <int W>
__global__ __launch_bounds__(256) void scatter_csr(const int* __restrict__ tmp,
                                                   const int* __restrict__ boff,
                                                   int* __restrict__ off,
                                                   int* __restrict__ csr, int n, int sub) {
    __shared__ int lcnt[W];
    __shared__ int lcur[W];
    int b = blockIdx.x;
    int t = threadIdx.x;
    int s = boff[b], e = boff[b + 1];
    if (t < W) lcnt[t] = 0;
    __syncthreads();
    for (int i = s + t; i < e; i += 256) atomicAdd(&lcnt[tmp[i] >> 20], 1);
    __syncthreads();
    if (t == 0) {
        int acc = s;
        for (int j = 0; j < W; j++) {
            lcur[j] = acc;
            acc += lcnt[j];
        }
    }
    __syncthreads();
    int base = b * W;
    if (t < W && base + t < n) off[base + t] = lcur[t] - sub;
    __syncthreads();
    for (int i = s + t; i < e; i += 256) {
        int v = tmp[i];
        int p = atomicAdd(&lcur[v >> 20], 1);
        csr[p - sub] = v & 0xFFFFF;
    }
}

// ---------------- segment mean (fp16 gather, one wave per dst row) ----------------
// Each lane loads 16 B = 8 halves. LPE = D/8 lanes per edge; GRP = 64/LPE edges/iter.

__device__ __forceinline__ void acc8(float* a, uint4 r) {
    const __half2* h = reinterpret_cast<const __half2*>(&r);
#pragma unroll
    for (int j = 0; j < 4; j++) {
        float2 f = __half22float2(h[j]);
        a[2 * j] += f.x;
        a[2 * j + 1] += f.y;
    }
}

template <int D>
__global__ __launch_bounds__(256) void agg_mean_h(const int* __restrict__ csr,
                                                  const int* __restrict__ off,
                                                  const __half* __restrict__ xh,
                                                  float* __restrict__ out, int nrows) {
    constexpr int LPE = D / 8;
    constexpr int GRP = 64 / LPE;
    int wave = (blockIdx.x * blockDim.x + threadIdx.x) >> 6;
    int lane = threadIdx.x & 63;
    int nwaves = (gridDim.x * blockDim.x) >> 6;
    int g = lane / LPE;
    int cl = lane % LPE;  // 8-col group
    for (int row = wave; row < nrows; row += nwaves) {
        int s = off[row], e = off[row + 1];
        float a[8] = {0.f, 0.f, 0.f, 0.f, 0.f, 0.f, 0.f, 0.f};
        for (int k = s + g; k < e; k += 2 * GRP) {
            int idx0 = csr[k];
            int k1 = k + GRP;
            int idx1 = (k1 < e) ? csr[k1] : -1;
            uint4 r0 = *(const uint4*)&xh[(long)idx0 * D + cl * 8];
            if (idx1 >= 0) {
                uint4 r1 = *(const uint4*)&xh[(long)idx1 * D + cl * 8];
                acc8(a, r0);
                acc8(a, r1);
            } else {
                acc8(a, r0);
            }
        }
        for (int m = LPE; m < 64; m <<= 1) {
#pragma unroll
            for (int j = 0; j < 8; j++) a[j] += __shfl_xor(a[j], m, 64);
        }
        if (g == 0) {
            float inv = 1.0f / fmaxf((float)(e - s), 1.0f);
            float4 r0 = make_float4(a[0] * inv, a[1] * inv, a[2] * inv, a[3] * inv);
            float4 r1 = make_float4(a[4] * inv, a[5] * inv, a[6] * inv, a[7] * inv);
            *(float4*)&out[(long)row * D + cl * 8] = r0;
            *(float4*)&out[(long)row * D + cl * 8 + 4] = r1;
        }
    }
}

// ---------------- dense: out = act([mean|xd] @ [Wl;Wr] + b) ----------------
// 64x64 tile per block, 256 threads, 4x4 register micro-tile. TX: xd dtype, TO: out dtype.

template <int Dm, int Dd, bool RELU, typename TX, typename TO>
__global__ __launch_bounds__(256) void dense_gemm(const float* __restrict__ mean,
                                                  const TX* __restrict__ xd,
                                                  const float* __restrict__ Wl,
                                                  const float* __restrict__ Wr,
                                                  const float* __restrict__ bias,
                                                  TO* __restrict__ out, int n) {
    constexpr int K = Dm + Dd;
    __shared__ float sA[64][K + 4];
    __shared__ float sW[K][68];
    __shared__ float sb[64];
    int t = threadIdx.x;
    int R0 = blockIdx.x * 64;

    for (int i = t; i < K * 16; i += 256) {
        int r = i >> 4, c = (i & 15) * 4;
        float4 v = (r < Dm) ? *(const float4*)&Wl[r * 64 + c]
                            : *(const float4*)&Wr[(r - Dm) * 64 + c];
        sW[r][c + 0] = v.x; sW[r][c + 1] = v.y; sW[r][c + 2] = v.z; sW[r][c + 3] = v.w;
    }
    if (t < 64) sb[t] = bias[t];
    constexpr int QR = K / 4;
    for (int i = t; i < 64 * QR; i += 256) {
        int r = i / QR, c = (i % QR) * 4;
        int gr = R0 + r;
        float4 v = make_float4(0.f, 0.f, 0.f, 0.f);
        if (gr < n) {
            if (c < Dm) {
                v = *(const float4*)&mean[(long)gr * Dm + c];
            } else {
                if constexpr (std::is_same<TX, __half>::value) {
                    const __half* p = &xd[(long)gr * Dd + (c - Dm)];
                    v = make_float4(__half2float(p[0]), __half2float(p[1]),
                                    __half2float(p[2]), __half2float(p[3]));
                } else {
                    v = *(const float4*)&xd[(long)gr * Dd + (c - Dm)];
                }
            }
        }
        sA[r][c + 0] = v.x; sA[r][c + 1] = v.y; sA[r][c + 2] = v.z; sA[r][c + 3] = v.w;
    }
    __syncthreads();

    int tx = t & 15, ty = t >> 4;
    int c0 = tx * 4, r0 = ty * 4;
    float acc[4][4];
    float4 bb = *(float4*)&sb[c0];
#pragma unroll
    for (int i = 0; i < 4; i++) {
        acc[i][0] = bb.x; acc[i][1] = bb.y; acc[i][2] = bb.z; acc[i][3] = bb.w;
    }
#pragma unroll 4
    for (int k = 0; k < K; k += 4) {
        float4 a[4], b[4];
#pragma unroll
        for (int i = 0; i < 4; i++) a[i] = *(float4*)&sA[r0 + i][k];
#pragma unroll
        for (int kk = 0; kk < 4; kk++) b[kk] = *(float4*)&sW[k + kk][c0];
#pragma unroll
        for (int i = 0; i < 4; i++) {
            acc[i][0] += a[i].x * b[0].x + a[i].y * b[1].x + a[i].z * b[2].x + a[i].w * b[3].x;
            acc[i][1] += a[i].x * b[0].y + a[i].y * b[1].y + a[i].z * b[2].y + a[i].w * b[3].y;
            acc[i][2] += a[i].x * b[0].z + a[i].y * b[1].z + a[i].z * b[2].z + a[i].w * b[3].z;
            acc[i][3] += a[i].x * b[0].w + a[i].y * b[1].w + a[i].z * b[2].w + a[i].w * b[3].w;
        }
    }
#pragma unroll
    for (int i = 0; i < 4; i++) {
        int gr = R0 + r0 + i;
        if (gr >= n) continue;
        float4 r;
        if (RELU) {
            r = make_float4(fmaxf(acc[i][0], 0.f), fmaxf(acc[i][1], 0.f),
                            fmaxf(acc[i][2], 0.f), fmaxf(acc[i][3], 0.f));
        } else {
            r = make_float4(acc[i][0], acc[i][1], acc[i][2], acc[i][3]);
        }
        if constexpr (std::is_same<TO, __half>::value) {
            __half2 h01 = __floats2half2_rn(r.x, r.y);
            __half2 h23 = __floats2half2_rn(r.z, r.w);
            *(__half2*)&out[(long)gr * 64 + c0] = h01;
            *(__half2*)&out[(long)gr * 64 + c0 + 2] = h23;
        } else {
            *(float4*)&out[(long)gr * 64 + c0] = r;
        }
    }
}

// ---------------- head ----------------

__global__ __launch_bounds__(256) void head_kernel(const float* __restrict__ z_user,
                                                   const float* __restrict__ z_movie,
                                                   const int* __restrict__ lrow,
                                                   const int* __restrict__ lcol,
                                                   const float* __restrict__ Wlin,
                                                   const float* __restrict__ blin,
                                                   float* __restrict__ out, int B) {
    int wave = (blockIdx.x * blockDim.x + threadIdx.x) >> 6;
    int lane = threadIdx.x & 63;
    int nw = (gridDim.x * blockDim.x) >> 6;
    for (int b = wave; b < B; b += nw) {
        int r = lrow[b], c = lcol[b];
        float zu = z_user[(long)r * 64 + lane];
        float zm = z_movie[(long)c * 64 + lane];
        float p0 = zu * Wlin[lane * 2 + 0] + zm * Wlin[(64 + lane) * 2 + 0];
        float p1 = zu * Wlin[lane * 2 + 1] + zm * Wlin[(64 + lane) * 2 + 1];
        for (int s = 32; s; s >>= 1) {
            p0 += __shfl_xor(p0, s, 64);
            p1 += __shfl_xor(p1, s, 64);
        }
        if (lane == 0) {
            float m = p0 + blin[0];
            float x = p1 + blin[1];
            float sp = fmaxf(x, 0.f) + log1pf(expf(-fabsf(x)));
            out[b] = m;
            out[B + b] = sp + 1e-6f;
        }
    }
}

// ---------------- launch ----------------

extern "C" void kernel_launch(void* const* d_in, const int* in_sizes, int n_in,
                              void* d_out, int out_size, void* d_ws, size_t ws_size,
                              hipStream_t stream) {
    const float* x_user  = (const float*)d_in[0];
    const float* x_movie = (const float*)d_in[1];
    const int* src_um = (const int*)d_in[2];
    const int* dst_um = (const int*)d_in[3];
    const int* src_mu = (const int*)d_in[4];
    const int* dst_mu = (const int*)d_in[5];
    const int* lrow = (const int*)d_in[6];
    const int* lcol = (const int*)d_in[7];
    const float* W1_um_l = (const float*)d_in[8];
    const float* b1_um   = (const float*)d_in[9];
    const float* W1_um_r = (const float*)d_in[10];
    const float* W1_mu_l = (const float*)d_in[11];
    const float* b1_mu   = (const float*)d_in[12];
    const float* W1_mu_r = (const float*)d_in[13];
    const float* W2_um_l = (const float*)d_in[14];
    const float* b2_um   = (const float*)d_in[15];
    const float* W2_um_r = (const float*)d_in[16];
    const float* W2_mu_l = (const float*)d_in[17];
    const float* b2_mu   = (const float*)d_in[18];
    const float* W2_mu_r = (const float*)d_in[19];
    const float* W_lin   = (const float*)d_in[20];
    const float* b_lin   = (const float*)d_in[21];
    float* out = (float*)d_out;

    const int E  = in_sizes[2];
    const int B  = in_sizes[6];
    const int NU = in_sizes[0] / 32;   // 100000
    const int NM = in_sizes[1] / 64;   // 20000

    char* wsp = (char*)d_ws;
    size_t o = 0;
    auto alloc = [&](size_t bytes) {
        size_t p = o;
        o += (bytes + 255) & ~(size_t)255;
        return (void*)(wsp + p);
    };
    int* off_um = (int*)alloc((size_t)(NM + 1) * 4);
    int* off_mu = (int*)alloc((size_t)(NU + 1) * 4);
    int* btot   = (int*)alloc((NBALL) * 4);
    int* boff   = (int*)alloc((NBALL + 1) * 4);
    int* csr_um = (int*)alloc((size_t)E * 4);
    int* csr_mu = (int*)alloc((size_t)E * 4);
    float* A_m  = (float*)alloc((size_t)NM * 64 * 4);   // movie mean / z_movie
    float* A_u  = (float*)alloc((size_t)NU * 64 * 4);   // user mean / z_user
    __half* Hh_m = (__half*)alloc((size_t)NM * 64 * 2); // h_movie fp16
    __half* Hh_u = (__half*)alloc((size_t)NU * 64 * 2); // h_user fp16
    __half* xh_u = (__half*)alloc((size_t)NU * 32 * 2); // x_user fp16
    __half* xh_m = (__half*)alloc((size_t)NM * 64 * 2); // x_movie fp16
    (void)ws_size;

    // aliases: consumed before their hosts are first written
    int* tmp   = (int*)A_u;   // [2E] ints = 16 MB <= 25.6 MB; dead after scatter_csr
    int* histM = (int*)A_m;   // 1.44 MB; dead after partition2; A_m first written by agg

    // 0) fp16 copies of input feature tables
    cast_half2<<<512, 256, 0, stream>>>(x_user, xh_u, NU * 32, x_movie, xh_m, NM * 64);

    // 1) CSR build (block-private radix partition)
    hist_part<<<NBLK, 1024, 0, stream>>>(dst_um, dst_mu, histM, E);
    bucket_totals<<<(NBALL + 3) / 4, 256, 0, stream>>>(histM, btot, NBALL);
    boff_scan<<<1, 256, 0, stream>>>(btot, boff, NBALL, off_um, NM, off_mu, NU, E);
    add_boff<<<352, 256, 0, stream>>>(histM, boff, NBALL * NBLK);
    partition2<<<NBLK, 1024, 0, stream>>>(src_um, dst_um, src_mu, dst_mu, histM, tmp, E);
    scatter_csr<32><<<NB_UM, 256, 0, stream>>>(tmp, boff, off_um, csr_um, NM, 0);
    scatter_csr<128><<<NB_MU, 256, 0, stream>>>(tmp, boff + NB_UM, off_mu, csr_mu, NU, E);

    // 2) layer 1
    agg_mean_h<32><<<(NM + 3) / 4, 256, 0, stream>>>(csr_um, off_um, xh_u, A_m, NM);
    dense_gemm<32, 64, true, float, __half><<<(NM + 63) / 64, 256, 0, stream>>>(
        A_m, x_movie, W1_um_l, W1_um_r, b1_um, Hh_m, NM);
    agg_mean_h<64><<<(NU + 3) / 4, 256, 0, stream>>>(csr_mu, off_mu, xh_m, A_u, NU);
    dense_gemm<64, 32, true, float, __half><<<(NU + 63) / 64, 256, 0, stream>>>(
        A_u, x_user, W1_mu_l, W1_mu_r, b1_mu, Hh_u, NU);

    // 3) layer 2 (dense in-place over the mean buffers; rows staged in LDS first)
    agg_mean_h<64><<<(NM + 3) / 4, 256, 0, stream>>>(csr_um, off_um, Hh_u, A_m, NM);
    dense_gemm<64, 64, false, __half, float><<<(NM + 63) / 64, 256, 0, stream>>>(
        A_m, Hh_m, W2_um_l, W2_um_r, b2_um, A_m, NM);
    agg_mean_h<64><<<(NU + 3) / 4, 256, 0, stream>>>(csr_mu, off_mu, Hh_m, A_u, NU);
    dense_gemm<64, 64, false, __half, float><<<(NU + 63) / 64, 256, 0, stream>>>(
        A_u, Hh_u, W2_mu_l, W2_mu_r, b2_mu, A_u, NU);

    // 4) head
    head_kernel<<<4096, 256, 0, stream>>>(A_u, A_m, lrow, lcol, W_lin, b_lin, out, B);
}